// Round 1
// baseline (494.026 us; speedup 1.0000x reference)
//
#include <hip/hip_runtime.h>
#include <cstdint>
#include <cstddef>

#define BB 64
#define NN 1024
#define DD 128

typedef short    bf16x8 __attribute__((ext_vector_type(8)));
typedef _Float16 f16x8  __attribute__((ext_vector_type(8)));
typedef float    f32x4  __attribute__((ext_vector_type(4)));

__device__ __forceinline__ unsigned short f2bf(float f) {
  union { float f; unsigned u; } v; v.f = f;
  unsigned r = v.u + 0x7FFFu + ((v.u >> 16) & 1u);
  return (unsigned short)(r >> 16);
}
__device__ __forceinline__ unsigned short f2h(float f) {
  union { _Float16 h; unsigned short u; } v; v.h = (_Float16)f;
  return v.u;
}
__device__ __forceinline__ float fast_tanh(float x) {
  x = fminf(15.0f, fmaxf(-15.0f, x));
  float e = __expf(2.0f * x);
  return (e - 1.0f) / (e + 1.0f);
}

// ---------------------------------------------------------------------------
// Kernel 1: q = tanh(x@Wq^T+bq) (fp16), k = tanh(x@Wk^T+bk) (fp16),
//           vT = tanh(x@Wv^T+bv) transposed (bf16, [b][h][n]).
// Block: 128 rows of x (all within one batch), 256 threads = 4 waves.
// ---------------------------------------------------------------------------
__global__ __launch_bounds__(256, 2) void proj_kernel(
    const float* __restrict__ x,
    const float* __restrict__ Wq, const float* __restrict__ bq,
    const float* __restrict__ Wk, const float* __restrict__ bk,
    const float* __restrict__ Wv, const float* __restrict__ bv,
    unsigned short* __restrict__ qg,   // fp16 [B][N][D]
    unsigned short* __restrict__ kg,   // fp16 [B][N][D]
    unsigned short* __restrict__ vtg)  // bf16 [B][D][N]
{
  __shared__ unsigned short wlds[128 * 136];  // weight tile bf16 (reused as vT stage)

  const int tid  = threadIdx.x;
  const int lane = tid & 63;
  const int wave = tid >> 6;
  const int quad = lane >> 4;
  const int mr   = lane & 15;
  const int m0   = blockIdx.x * 128;     // flat row b*N+n
  const int batch = m0 >> 10;
  const int n0    = m0 & 1023;

  // Preload x A-frags as bf16: rows wave*32+mt*16+mr, k = ks*32+quad*8+j
  bf16x8 xa[2][4];
#pragma unroll
  for (int mt = 0; mt < 2; ++mt) {
    const float* xr = x + (size_t)(m0 + wave * 32 + mt * 16 + mr) * DD + quad * 8;
#pragma unroll
    for (int ks = 0; ks < 4; ++ks) {
      const float4* xp = (const float4*)(xr + ks * 32);
      float4 f0 = xp[0], f1 = xp[1];
      bf16x8 f;
      f[0] = (short)f2bf(f0.x); f[1] = (short)f2bf(f0.y);
      f[2] = (short)f2bf(f0.z); f[3] = (short)f2bf(f0.w);
      f[4] = (short)f2bf(f1.x); f[5] = (short)f2bf(f1.y);
      f[6] = (short)f2bf(f1.z); f[7] = (short)f2bf(f1.w);
      xa[mt][ks] = f;
    }
  }

  const float* Wp[3] = {Wq, Wk, Wv};
  const float* bp[3] = {bq, bk, bv};

  for (int w = 0; w < 3; ++w) {
    __syncthreads();  // previous weight's LDS reads done
    {
      const int row = tid >> 1, half = tid & 1;
      const float* src = Wp[w] + row * 128 + half * 64;
      unsigned short* dst = wlds + row * 136 + half * 64;
#pragma unroll
      for (int c = 0; c < 64; c += 8) {
        const float4* sp = (const float4*)(src + c);
        float4 f0 = sp[0], f1 = sp[1];
        unsigned short tmp[8];
        tmp[0] = f2bf(f0.x); tmp[1] = f2bf(f0.y); tmp[2] = f2bf(f0.z); tmp[3] = f2bf(f0.w);
        tmp[4] = f2bf(f1.x); tmp[5] = f2bf(f1.y); tmp[6] = f2bf(f1.z); tmp[7] = f2bf(f1.w);
        uint4 pk; __builtin_memcpy(&pk, tmp, 16);
        *(uint4*)(dst + c) = pk;
      }
    }
    __syncthreads();

    f32x4 z = {0.f, 0.f, 0.f, 0.f};
    f32x4 acc[2][8];
#pragma unroll
    for (int mt = 0; mt < 2; ++mt)
#pragma unroll
      for (int nt = 0; nt < 8; ++nt) acc[mt][nt] = z;

#pragma unroll
    for (int ks = 0; ks < 4; ++ks) {
#pragma unroll
      for (int nt = 0; nt < 8; ++nt) {
        bf16x8 bfr = *(const bf16x8*)(wlds + (nt * 16 + mr) * 136 + ks * 32 + quad * 8);
        acc[0][nt] = __builtin_amdgcn_mfma_f32_16x16x32_bf16(xa[0][ks], bfr, acc[0][nt], 0, 0, 0);
        acc[1][nt] = __builtin_amdgcn_mfma_f32_16x16x32_bf16(xa[1][ks], bfr, acc[1][nt], 0, 0, 0);
      }
    }

    if (w < 2) {
      unsigned short* outg = (w == 0) ? qg : kg;
#pragma unroll
      for (int mt = 0; mt < 2; ++mt) {
        const int rowbase = m0 + wave * 32 + mt * 16 + quad * 4;
#pragma unroll
        for (int nt = 0; nt < 8; ++nt) {
          float bb = bp[w][nt * 16 + mr];
#pragma unroll
          for (int r = 0; r < 4; ++r) {
            float t = fast_tanh(acc[mt][nt][r] + bb);
            outg[(size_t)(rowbase + r) * DD + nt * 16 + mr] = f2h(t);
          }
        }
      }
    } else {
      // v: transpose via wlds then coalesced store to vtg[b][h][n]
      __syncthreads();  // all B-frag reads of wlds finished
#pragma unroll
      for (int mt = 0; mt < 2; ++mt) {
        const int ib = wave * 32 + mt * 16 + quad * 4;
#pragma unroll
        for (int nt = 0; nt < 8; ++nt) {
          float bb = bp[2][nt * 16 + mr];
#pragma unroll
          for (int r = 0; r < 4; ++r) {
            float t = fast_tanh(acc[mt][nt][r] + bb);
            wlds[(nt * 16 + mr) * 136 + ib + r] = f2bf(t);
          }
        }
      }
      __syncthreads();
      const int h = tid >> 1, half = tid & 1;
      const unsigned short* src = wlds + h * 136 + half * 64;
      unsigned short* dst = vtg + (size_t)(batch * 128 + h) * NN + n0 + half * 64;
#pragma unroll
      for (int c = 0; c < 64; c += 8)
        *(uint4*)(dst + c) = *(const uint4*)(src + c);
    }
  }
}

// ---------------------------------------------------------------------------
// Kernel 2: flash-style masked attention, no row-max (scores are O(30)).
// Block = (batch, 128 q-rows); 16 j-tiles of 64. Row-sum via ones-row MFMA.
// ---------------------------------------------------------------------------
__global__ __launch_bounds__(256, 2) void attn_kernel(
    const unsigned short* __restrict__ qg,
    const unsigned short* __restrict__ kg,
    const unsigned short* __restrict__ vtg,
    const int* __restrict__ mask,
    float* __restrict__ out)
{
  __shared__ unsigned short klds[64 * 136];    // [j][h] fp16, padded
  __shared__ unsigned short vtlds[144 * 72];   // [h][j] bf16; row128=ones, 129..143=0
  __shared__ unsigned short plds[128 * 88];    // [i][j] bf16, padded

  const int tid  = threadIdx.x;
  const int lane = tid & 63;
  const int wave = tid >> 6;
  const int quad = lane >> 4;
  const int mr   = lane & 15;

  const int bx    = blockIdx.x;
  const int batch = (bx & 7) * 8 + ((bx >> 3) & 7);  // same-batch blocks -> same XCD
  const int i0    = (bx >> 6) * 128;

  // ones/zeros rows for the row-sum trick
  for (int idx = tid; idx < 16 * 72; idx += 256) {
    int rr = idx / 72, cc = idx % 72;
    vtlds[(128 + rr) * 72 + cc] = (rr == 0) ? (unsigned short)0x3F80 : (unsigned short)0;
  }

  // Preload Q A-frags (fp16)
  f16x8 qa[2][4];
#pragma unroll
  for (int mt = 0; mt < 2; ++mt)
#pragma unroll
    for (int ks = 0; ks < 4; ++ks)
      qa[mt][ks] = *(const f16x8*)(qg +
          ((size_t)batch * NN + i0 + wave * 32 + mt * 16 + mr) * DD + ks * 32 + quad * 8);

  f32x4 z = {0.f, 0.f, 0.f, 0.f};
  f32x4 o[2][9];
#pragma unroll
  for (int mt = 0; mt < 2; ++mt)
#pragma unroll
    for (int nt = 0; nt < 9; ++nt) o[mt][nt] = z;

  const unsigned short* kgb = kg  + (size_t)batch * NN * DD;
  const unsigned short* vtb = vtg + (size_t)batch * DD * NN;
  const int* mbase = mask + ((size_t)batch << 20);

  const int kj = tid >> 2, ksg = (tid & 3) * 32;  // K stage: 32 elems/thread
  const int vh = tid >> 1, vsg = (tid & 1) * 32;  // VT stage: 32 elems/thread

  uint4 kst[4], vst[4];
  {
    const uint4* s1 = (const uint4*)(kgb + (size_t)kj * DD + ksg);
    const uint4* s2 = (const uint4*)(vtb + (size_t)vh * NN + vsg);
#pragma unroll
    for (int c = 0; c < 4; ++c) { kst[c] = s1[c]; vst[c] = s2[c]; }
  }

  for (int t = 0; t < 16; ++t) {
    const int j0 = t * 64;

    // mask loads for this tile (in flight across the barriers + staging)
    int mv[2][4][4];
#pragma unroll
    for (int mt = 0; mt < 2; ++mt) {
      const int* mrow0 = mbase + (size_t)(i0 + wave * 32 + mt * 16 + quad * 4) * NN + j0 + mr;
#pragma unroll
      for (int r = 0; r < 4; ++r)
#pragma unroll
        for (int nt = 0; nt < 4; ++nt)
          mv[mt][nt][r] = mrow0[r * NN + nt * 16];
    }

    __syncthreads();  // previous iter's LDS reads done
    {
      uint4* d1 = (uint4*)(klds + kj * 136 + ksg);
      uint4* d2 = (uint4*)(vtlds + vh * 72 + vsg);
#pragma unroll
      for (int c = 0; c < 4; ++c) d1[c] = kst[c];
#pragma unroll
      for (int c = 0; c < 4; ++c) d2[c] = vst[c];
    }
    __syncthreads();

    // prefetch next tile (wraps at the end; discarded)
    {
      const int j0n = ((t + 1) & 15) * 64;
      const uint4* s1 = (const uint4*)(kgb + (size_t)(j0n + kj) * DD + ksg);
      const uint4* s2 = (const uint4*)(vtb + (size_t)vh * NN + j0n + vsg);
#pragma unroll
      for (int c = 0; c < 4; ++c) { kst[c] = s1[c]; vst[c] = s2[c]; }
    }

    // S = Q @ K^T  (fp16 MFMA)
    f32x4 s[2][4];
#pragma unroll
    for (int mt = 0; mt < 2; ++mt)
#pragma unroll
      for (int nt = 0; nt < 4; ++nt) s[mt][nt] = z;
#pragma unroll
    for (int ks = 0; ks < 4; ++ks) {
#pragma unroll
      for (int nt = 0; nt < 4; ++nt) {
        f16x8 kb = *(const f16x8*)(klds + (nt * 16 + mr) * 136 + ks * 32 + quad * 8);
        s[0][nt] = __builtin_amdgcn_mfma_f32_16x16x32_f16(qa[0][ks], kb, s[0][nt], 0, 0, 0);
        s[1][nt] = __builtin_amdgcn_mfma_f32_16x16x32_f16(qa[1][ks], kb, s[1][nt], 0, 0, 0);
      }
    }

    // P = mask ? exp(S) : 0  -> bf16 -> LDS
#pragma unroll
    for (int mt = 0; mt < 2; ++mt) {
      const int ib = wave * 32 + mt * 16 + quad * 4;
#pragma unroll
      for (int nt = 0; nt < 4; ++nt) {
#pragma unroll
        for (int r = 0; r < 4; ++r) {
          float e = __expf(s[mt][nt][r]);
          e = (mv[mt][nt][r] != 0) ? e : 0.0f;
          plds[(ib + r) * 88 + nt * 16 + mr] = f2bf(e);
        }
      }
    }
    __syncthreads();

    // O += P @ V ; nt==8 accumulates row sums against the ones-row
#pragma unroll
    for (int ks = 0; ks < 2; ++ks) {
      bf16x8 pa0 = *(const bf16x8*)(plds + (wave * 32 + mr) * 88 + ks * 32 + quad * 8);
      bf16x8 pa1 = *(const bf16x8*)(plds + (wave * 32 + 16 + mr) * 88 + ks * 32 + quad * 8);
#pragma unroll
      for (int nt = 0; nt < 9; ++nt) {
        bf16x8 vb = *(const bf16x8*)(vtlds + (nt * 16 + mr) * 72 + ks * 32 + quad * 8);
        o[0][nt] = __builtin_amdgcn_mfma_f32_16x16x32_bf16(pa0, vb, o[0][nt], 0, 0, 0);
        o[1][nt] = __builtin_amdgcn_mfma_f32_16x16x32_bf16(pa1, vb, o[1][nt], 0, 0, 0);
      }
    }
  }

  // epilogue: normalize and store fp32
  float* ob = out + (size_t)batch * NN * DD;
#pragma unroll
  for (int mt = 0; mt < 2; ++mt) {
    const int rowbase = i0 + wave * 32 + mt * 16 + quad * 4;
#pragma unroll
    for (int r = 0; r < 4; ++r) {
      float rs  = __shfl(o[mt][8][r], lane & 48, 64);  // col 0 of ones-tile
      float inv = 1.0f / rs;
#pragma unroll
      for (int nt = 0; nt < 8; ++nt)
        ob[(size_t)(rowbase + r) * DD + nt * 16 + mr] = o[mt][nt][r] * inv;
    }
  }
}

// ---------------------------------------------------------------------------
extern "C" void kernel_launch(void* const* d_in, const int* in_sizes, int n_in,
                              void* d_out, int out_size, void* d_ws, size_t ws_size,
                              hipStream_t stream) {
  (void)in_sizes; (void)n_in; (void)out_size; (void)ws_size;
  const float* x  = (const float*)d_in[0];
  const int* mask = (const int*)d_in[1];
  const float* Wv = (const float*)d_in[2];
  const float* bv = (const float*)d_in[3];
  const float* Wk = (const float*)d_in[4];
  const float* bk = (const float*)d_in[5];
  const float* Wq = (const float*)d_in[6];
  const float* bq = (const float*)d_in[7];
  float* out = (float*)d_out;

  unsigned short* qg  = (unsigned short*)d_ws;          // fp16 [B][N][D]
  unsigned short* kg  = qg + (size_t)BB * NN * DD;      // fp16 [B][N][D]
  unsigned short* vtg = kg + (size_t)BB * NN * DD;      // bf16 [B][D][N]

  proj_kernel<<<512, 256, 0, stream>>>(x, Wq, bq, Wk, bk, Wv, bv, qg, kg, vtg);
  attn_kernel<<<512, 256, 0, stream>>>(qg, kg, vtg, mask, out);
}